// Round 2
// baseline (51.019 us; speedup 1.0000x reference)
//
#include <hip/hip_runtime.h>
#include <math.h>

#define D 20
#define BATCH_ROWS 1000000
#define BLOCK 256
#define NB ((BATCH_ROWS + BLOCK - 1) / BLOCK)   // 3907 blocks
#define ROW_F4 5                                 // float4s per row
#define LDS_STRIDE 21                            // 21 floats/row: coprime with 32 banks

// ws layout (every region written before read on each launch -> poison-safe):
//   [0, NB*2*8)          : per-block partial sums (S, Sabs) doubles = 62512 B
//   [62720, +1600)       : A = W^T @ R   (20x20 floats)
//   [64320, +80)         : c = b @ R + 1 (20 floats)
#define A_OFF 62720
#define C_OFF (A_OFF + D*D*4)

// ---------------------------------------------------------------------------
// Setup: fold the first two linear layers.
//   A[j][m] = sum_i W[i][j] * R[i][m];  c[m] = 1 + sum_i b[i] * R[i][m]
// ---------------------------------------------------------------------------
__global__ __launch_bounds__(512) void setup_kernel(
    const float* __restrict__ W, const float* __restrict__ b,
    const float* __restrict__ R, float* __restrict__ A, float* __restrict__ c) {
  int t = threadIdx.x;
  if (t < D * D) {
    int j = t / D, m = t % D;
    float s = 0.f;
#pragma unroll
    for (int i = 0; i < D; ++i) s = fmaf(W[i * D + j], R[i * D + m], s);
    A[j * D + m] = s;
  } else if (t < D * D + D) {
    int m = t - D * D;
    float s = 1.0f;
#pragma unroll
    for (int i = 0; i < D; ++i) s = fmaf(b[i], R[i * D + m], s);
    c[m] = s;
  }
}

// ---------------------------------------------------------------------------
// Main: block stages 256 rows of X into LDS (coalesced float4 global loads,
// rows padded to 21 floats so stride-21 ds_read_b32 is bank-conflict-free),
// then one thread per row:
//   X2 = relu(x @ A + c);  x3[n] = b[n] + sum_m X2[m]*W[n][m]  (W contiguous!)
// A/W/b/c are wave-uniform -> scalar loads; W now read contiguously in m.
// ---------------------------------------------------------------------------
__global__ __launch_bounds__(BLOCK) void main_kernel(
    const float* __restrict__ X, const float* __restrict__ W,
    const float* __restrict__ b, const float* __restrict__ A,
    const float* __restrict__ c, double* __restrict__ partial) {
  __shared__ float xs[BLOCK * LDS_STRIDE];   // 21504 B
  const int t = threadIdx.x;

  // ---- stage: 1280 float4s per block, fully coalesced ----
  const float4* X4 = (const float4*)X;
  const long gbase = (long)blockIdx.x * (BLOCK * ROW_F4);
#pragma unroll
  for (int j = 0; j < ROW_F4; ++j) {
    long idx = gbase + j * BLOCK + t;
    if (idx < (long)BATCH_ROWS * ROW_F4) {
      float4 v = X4[idx];
      int il = j * BLOCK + t;            // local float4 index 0..1279
      int r = il / ROW_F4, p = il % ROW_F4;
      float* dst = &xs[r * LDS_STRIDE + p * 4];
      dst[0] = v.x; dst[1] = v.y; dst[2] = v.z; dst[3] = v.w;
    }
  }
  __syncthreads();

  // ---- compute: one row per thread ----
  const int row = blockIdx.x * BLOCK + t;
  float s = 0.f, sa = 0.f;
  if (row < BATCH_ROWS) {
    float x[D];
#pragma unroll
    for (int k = 0; k < D; ++k) x[k] = xs[t * LDS_STRIDE + k];

    float acc[D];
#pragma unroll
    for (int m = 0; m < D; ++m) acc[m] = c[m];
#pragma unroll
    for (int j = 0; j < D; ++j) {
#pragma unroll
      for (int m = 0; m < D; ++m) acc[m] = fmaf(x[j], A[j * D + m], acc[m]);
    }
#pragma unroll
    for (int m = 0; m < D; ++m) acc[m] = fmaxf(acc[m], 0.f);  // relu -> X2

#pragma unroll
    for (int n = 0; n < D; ++n) {       // W[n][m] contiguous in m
      float o = b[n];
#pragma unroll
      for (int m = 0; m < D; ++m) o = fmaf(acc[m], W[n * D + m], o);
      s += o; sa += fabsf(o);
    }
  }

  // ---- reduce: wave64 shfl in double, then 4-wave LDS, 1 write/block ----
  double ds = (double)s, da = (double)sa;
#pragma unroll
  for (int off = 32; off > 0; off >>= 1) {
    ds += __shfl_down(ds, off, 64);
    da += __shfl_down(da, off, 64);
  }
  __shared__ double red[8];
  int wid = t >> 6;
  if ((t & 63) == 0) { red[wid * 2] = ds; red[wid * 2 + 1] = da; }
  __syncthreads();
  if (t == 0) {
    partial[2 * blockIdx.x]     = red[0] + red[2] + red[4] + red[6];
    partial[2 * blockIdx.x + 1] = red[1] + red[3] + red[5] + red[7];
  }
}

// ---------------------------------------------------------------------------
// Finalize: reduce 3907 partial pairs; the while-loop is exact scalar math:
// k = #halvings until abs-sum <= 1; out = ldexp(S, -k).
// ---------------------------------------------------------------------------
__global__ __launch_bounds__(256) void final_kernel(
    const double* __restrict__ partial, float* __restrict__ out) {
  double s = 0.0, sa = 0.0;
  for (int i = threadIdx.x; i < NB; i += 256) {
    s += partial[2 * i];
    sa += partial[2 * i + 1];
  }
#pragma unroll
  for (int off = 32; off > 0; off >>= 1) {
    s += __shfl_down(s, off, 64);
    sa += __shfl_down(sa, off, 64);
  }
  __shared__ double red[8];
  int wid = threadIdx.x >> 6;
  if ((threadIdx.x & 63) == 0) { red[wid * 2] = s; red[wid * 2 + 1] = sa; }
  __syncthreads();
  if (threadIdx.x == 0) {
    double S  = red[0] + red[2] + red[4] + red[6];
    double SA = red[1] + red[3] + red[5] + red[7];
    int k = 0;
    double t = SA;
    while (t > 1.0 && k < 4096) { t *= 0.5; ++k; }  // exact: /2 per ref iter
    out[0] = (float)ldexp(S, -k);
  }
}

extern "C" void kernel_launch(void* const* d_in, const int* in_sizes, int n_in,
                              void* d_out, int out_size, void* d_ws, size_t ws_size,
                              hipStream_t stream) {
  const float* X = (const float*)d_in[0];
  const float* W = (const float*)d_in[1];
  const float* b = (const float*)d_in[2];
  const float* R = (const float*)d_in[3];
  char* ws = (char*)d_ws;
  double* partial = (double*)ws;
  float* A = (float*)(ws + A_OFF);
  float* c = (float*)(ws + C_OFF);

  setup_kernel<<<1, 512, 0, stream>>>(W, b, R, A, c);
  main_kernel<<<NB, BLOCK, 0, stream>>>(X, W, b, A, c, partial);
  final_kernel<<<1, 256, 0, stream>>>(partial, (float*)d_out);
}

// Round 3
// 30.381 us; speedup vs baseline: 1.6793x; 1.6793x over previous
//
#include <hip/hip_runtime.h>
#include <math.h>

#define D 20
#define NROWS 1000000
#define NTILES (NROWS / 16)                  // 62500 16-row tiles
#define TPB 256
#define MAIN_BLOCKS 1024
#define WAVES_TOTAL (MAIN_BLOCKS * (TPB/64)) // 4096 waves

typedef float  f32x4  __attribute__((ext_vector_type(4)));
typedef __bf16 bf16x8 __attribute__((ext_vector_type(8)));

// ws layout (all regions written before read every launch -> poison-safe):
//   [0, 16384)       : per-block partials (S, Sabs) as doubles
//   [16384, +4096)   : 4 MFMA constant fragments, 64 lanes x 16B each
#define FRAG_OFF (MAIN_BLOCKS * 2 * 8)

__device__ inline unsigned int pk2(float a, float b) {
  unsigned short la = __builtin_bit_cast(unsigned short, (__bf16)a);
  unsigned short lb = __builtin_bit_cast(unsigned short, (__bf16)b);
  return (unsigned int)la | ((unsigned int)lb << 16);
}

// ---------------------------------------------------------------------------
// Setup: fold layers + build MFMA constant fragments.
//   A[j][m] = sum_i W[i][j]*R[i][m];  c[m] = 1 + sum_i b[i]*R[i][m]
// Fragments (16x16x32 bf16 layout: lane l holds k = (l>>4)*8+e, e=0..7):
//   B1t1/B1t2: A^T as MFMA-A-operand rows m=ii / 16+ii, k=j; k==20 slot = c[m]
//   B2t1/B2t2: W  as MFMA-B-operand cols n=ii / 16+ii, with SIGMA-permuted
//              k-rows sigma(G,e) = e<4 ? 4G+e : 16+4G+(e-4); slot sigma==20 = b[n]
// ---------------------------------------------------------------------------
__global__ __launch_bounds__(512) void setup_kernel(
    const float* __restrict__ W, const float* __restrict__ b,
    const float* __restrict__ R, unsigned int* __restrict__ frags) {
  __shared__ float A_s[D * D];
  __shared__ float c_s[D];
  const int t = threadIdx.x;
  if (t < D * D) {
    int j = t / D, m = t % D;
    float s = 0.f;
#pragma unroll
    for (int i = 0; i < D; ++i) s = fmaf(W[i * D + j], R[i * D + m], s);
    A_s[j * D + m] = s;
  } else if (t < D * D + D) {
    int m = t - D * D;
    float s = 1.0f;
#pragma unroll
    for (int i = 0; i < D; ++i) s = fmaf(b[i], R[i * D + m], s);
    c_s[m] = s;
  }
  __syncthreads();
  if (t < 64) {
    const int G = t >> 4, ii = t & 15;
    uint4* out = (uint4*)frags;
    // vA(k,m): GEMM1 A^T-operand value (k indexes j; k==20 carries c)
    // vW(k,n): GEMM2 B-operand value (k indexes m; k==20 carries b)
    unsigned w[4];
    // ---- B1t1: rows m = ii ----
    for (int wd = 0; wd < 4; ++wd) {
      float v[2];
      for (int h = 0; h < 2; ++h) {
        int k = G * 8 + 2 * wd + h;
        v[h] = (k < D) ? A_s[k * D + ii] : (k == D ? c_s[ii] : 0.f);
      }
      w[wd] = pk2(v[0], v[1]);
    }
    out[t] = make_uint4(w[0], w[1], w[2], w[3]);
    // ---- B1t2: rows m = 16+ii (zero if >=20) ----
    for (int wd = 0; wd < 4; ++wd) {
      float v[2];
      for (int h = 0; h < 2; ++h) {
        int k = G * 8 + 2 * wd + h;
        int m = 16 + ii;
        v[h] = (m < D) ? ((k < D) ? A_s[k * D + m] : (k == D ? c_s[m] : 0.f)) : 0.f;
      }
      w[wd] = pk2(v[0], v[1]);
    }
    out[64 + t] = make_uint4(w[0], w[1], w[2], w[3]);
    // ---- B2t1: cols n = ii, sigma-permuted k-rows ----
    for (int wd = 0; wd < 4; ++wd) {
      float v[2];
      for (int h = 0; h < 2; ++h) {
        int e = 2 * wd + h;
        int sg = (e < 4) ? (4 * G + e) : (16 + 4 * G + (e - 4));
        v[h] = (sg < D) ? W[ii * D + sg] : (sg == D ? b[ii] : 0.f);
      }
      w[wd] = pk2(v[0], v[1]);
    }
    out[128 + t] = make_uint4(w[0], w[1], w[2], w[3]);
    // ---- B2t2: cols n = 16+ii (zero if >=20) ----
    for (int wd = 0; wd < 4; ++wd) {
      float v[2];
      for (int h = 0; h < 2; ++h) {
        int e = 2 * wd + h;
        int sg = (e < 4) ? (4 * G + e) : (16 + 4 * G + (e - 4));
        int n = 16 + ii;
        v[h] = (n < D) ? ((sg < D) ? W[n * D + sg] : (sg == D ? b[n] : 0.f)) : 0.f;
      }
      w[wd] = pk2(v[0], v[1]);
    }
    out[192 + t] = make_uint4(w[0], w[1], w[2], w[3]);
  }
}

// ---------------------------------------------------------------------------
// Main: per 16-row tile, per wave (grid-stride), no LDS in the loop:
//   X-frag: lane l holds X[r=l&15][k=G*8+e] (k==20 -> 1.0 for the c-slot)
//   GEMM1 (transposed): a1/a2 = mfma(B1t*, Xfrag) -> lane holds
//       X2[r=l&15][4G+reg] and X2[r][16+4G+reg]  (== GEMM2 A-frag slots!)
//   relu; hijack m=20 slot (G==1, reg0) to 1.0 for the b-row.
//   GEMM2: z = mfma(X2frag, B2t*) -> Z[4G+reg][n]; sum / abs-sum.
// ---------------------------------------------------------------------------
__global__ __launch_bounds__(TPB) void main_kernel(
    const float* __restrict__ X, const unsigned int* __restrict__ frags,
    double* __restrict__ partial) {
  const int tid = threadIdx.x;
  const int lane = tid & 63;
  const int G = lane >> 4, ii = lane & 15;
  const int wid = tid >> 6;
  const int gwave = blockIdx.x * (TPB / 64) + wid;

  const uint4* fr = (const uint4*)frags;
  const bf16x8 B1t1 = __builtin_bit_cast(bf16x8, fr[lane]);
  const bf16x8 B1t2 = __builtin_bit_cast(bf16x8, fr[64 + lane]);
  const bf16x8 B2t1 = __builtin_bit_cast(bf16x8, fr[128 + lane]);
  const bf16x8 B2t2 = __builtin_bit_cast(bf16x8, fr[192 + lane]);

  const int g8 = (G < 2) ? G * 8 : 16;
  double s64 = 0.0, sa64 = 0.0;

  // one-tile-ahead prefetch of this lane's 16B(+16B) slice
  float4 xa = {0.f, 0.f, 0.f, 0.f}, xb = {0.f, 0.f, 0.f, 0.f};
  if (gwave < NTILES) {
    const float* p = X + (size_t)(gwave * 16 + ii) * D + g8;
    if (G < 3) xa = *(const float4*)p;
    if (G < 2) xb = *(const float4*)(p + 4);
  }

  for (int t = gwave; t < NTILES; t += WAVES_TOTAL) {
    const float4 ca = xa, cb = xb;
    const int tn = t + WAVES_TOTAL;
    xa = (float4){0.f, 0.f, 0.f, 0.f};
    xb = (float4){0.f, 0.f, 0.f, 0.f};
    if (tn < NTILES) {
      const float* p = X + (size_t)(tn * 16 + ii) * D + g8;
      if (G < 3) xa = *(const float4*)p;
      if (G < 2) xb = *(const float4*)(p + 4);
    }
    // build X fragment (c-slot k=20 -> 1.0 on G==2/e==4)
    const float e4 = (G == 2) ? 1.0f : cb.x;
    bf16x8 xf;
    xf[0] = (__bf16)ca.x; xf[1] = (__bf16)ca.y;
    xf[2] = (__bf16)ca.z; xf[3] = (__bf16)ca.w;
    xf[4] = (__bf16)e4;   xf[5] = (__bf16)cb.y;
    xf[6] = (__bf16)cb.z; xf[7] = (__bf16)cb.w;

    const f32x4 zz = {0.f, 0.f, 0.f, 0.f};
    f32x4 a1 = __builtin_amdgcn_mfma_f32_16x16x32_bf16(B1t1, xf, zz, 0, 0, 0);
    f32x4 a2 = __builtin_amdgcn_mfma_f32_16x16x32_bf16(B1t2, xf, zz, 0, 0, 0);
#pragma unroll
    for (int q = 0; q < 4; ++q) {
      a1[q] = fmaxf(a1[q], 0.f);
      a2[q] = fmaxf(a2[q], 0.f);
    }
    const float hj = (G == 1) ? 1.0f : a2[0];  // m=20 slot carries 1.0 (b-row)
    bf16x8 x2f;
    x2f[0] = (__bf16)a1[0]; x2f[1] = (__bf16)a1[1];
    x2f[2] = (__bf16)a1[2]; x2f[3] = (__bf16)a1[3];
    x2f[4] = (__bf16)hj;    x2f[5] = (__bf16)a2[1];
    x2f[6] = (__bf16)a2[2]; x2f[7] = (__bf16)a2[3];

    f32x4 z1 = __builtin_amdgcn_mfma_f32_16x16x32_bf16(x2f, B2t1, zz, 0, 0, 0);
    f32x4 z2 = __builtin_amdgcn_mfma_f32_16x16x32_bf16(x2f, B2t2, zz, 0, 0, 0);

    const float s8 = ((z1[0] + z1[1]) + (z1[2] + z1[3])) +
                     ((z2[0] + z2[1]) + (z2[2] + z2[3]));
    const float sa8 = ((fabsf(z1[0]) + fabsf(z1[1])) + (fabsf(z1[2]) + fabsf(z1[3]))) +
                      ((fabsf(z2[0]) + fabsf(z2[1])) + (fabsf(z2[2]) + fabsf(z2[3])));
    s64 += (double)s8;
    sa64 += (double)sa8;
  }

  // wave64 f64 reduce, then 4-wave LDS reduce, one partial pair per block
#pragma unroll
  for (int off = 32; off > 0; off >>= 1) {
    s64 += __shfl_down(s64, off, 64);
    sa64 += __shfl_down(sa64, off, 64);
  }
  __shared__ double red[8];
  if ((tid & 63) == 0) { red[wid * 2] = s64; red[wid * 2 + 1] = sa64; }
  __syncthreads();
  if (tid == 0) {
    partial[2 * blockIdx.x]     = red[0] + red[2] + red[4] + red[6];
    partial[2 * blockIdx.x + 1] = red[1] + red[3] + red[5] + red[7];
  }
}

// ---------------------------------------------------------------------------
// Finalize: reduce per-block pairs; while-loop is exact scalar math:
// k = #halvings until abs-sum <= 1; out = ldexp(S, -k).
// ---------------------------------------------------------------------------
__global__ __launch_bounds__(256) void final_kernel(
    const double* __restrict__ partial, float* __restrict__ out) {
  double s = 0.0, sa = 0.0;
  for (int i = threadIdx.x; i < MAIN_BLOCKS; i += 256) {
    s += partial[2 * i];
    sa += partial[2 * i + 1];
  }
#pragma unroll
  for (int off = 32; off > 0; off >>= 1) {
    s += __shfl_down(s, off, 64);
    sa += __shfl_down(sa, off, 64);
  }
  __shared__ double red[8];
  int wid = threadIdx.x >> 6;
  if ((threadIdx.x & 63) == 0) { red[wid * 2] = s; red[wid * 2 + 1] = sa; }
  __syncthreads();
  if (threadIdx.x == 0) {
    double S  = red[0] + red[2] + red[4] + red[6];
    double SA = red[1] + red[3] + red[5] + red[7];
    int k = 0;
    double t = SA;
    while (t > 1.0 && k < 4096) { t *= 0.5; ++k; }  // exact: /2 per ref iter
    out[0] = (float)ldexp(S, -k);
  }
}

extern "C" void kernel_launch(void* const* d_in, const int* in_sizes, int n_in,
                              void* d_out, int out_size, void* d_ws, size_t ws_size,
                              hipStream_t stream) {
  const float* X = (const float*)d_in[0];
  const float* W = (const float*)d_in[1];
  const float* b = (const float*)d_in[2];
  const float* R = (const float*)d_in[3];
  char* ws = (char*)d_ws;
  double* partial = (double*)ws;
  unsigned int* frags = (unsigned int*)(ws + FRAG_OFF);

  setup_kernel<<<1, 512, 0, stream>>>(W, b, R, frags);
  main_kernel<<<MAIN_BLOCKS, TPB, 0, stream>>>(X, frags, partial);
  final_kernel<<<1, 256, 0, stream>>>(partial, (float*)d_out);
}